// Round 6
// baseline (336.843 us; speedup 1.0000x reference)
//
#include <hip/hip_runtime.h>

typedef unsigned short u16;
typedef __bf16 bf16x8 __attribute__((ext_vector_type(8)));
typedef unsigned short u16x8 __attribute__((ext_vector_type(8)));
typedef float f32x4 __attribute__((ext_vector_type(4)));

// ---------- helpers ----------
__device__ __forceinline__ u16 f2bf(float f) {
    unsigned u = __float_as_uint(f);
    unsigned r = u + 0x7fffu + ((u >> 16) & 1u);   // round-to-nearest-even
    return (u16)(r >> 16);
}
__device__ __forceinline__ float bf2f(u16 v) {
    return __uint_as_float(((unsigned)v) << 16);
}

__device__ __forceinline__ void async16(const void* g, void* l) {
    // global -> LDS direct copy, 16B per lane. LDS dest linear per wave.
    __builtin_amdgcn_global_load_lds(
        (__attribute__((address_space(1))) void*)(unsigned long long)g,
        (__attribute__((address_space(3))) void*)l, 16, 0, 0);
}

__device__ __forceinline__ bf16x8 ld8(const u16* p) {
    return __builtin_bit_cast(bf16x8, *(const u16x8*)p);
}

// ---------- weight convert: wcat=[w_phi;w_theta] (512x512), wg (256x512), wm (512x256) ----------
__global__ __launch_bounds__(256) void convert_w(
        const float* __restrict__ wphi, const float* __restrict__ wtheta,
        const float* __restrict__ wg, const float* __restrict__ wm,
        u16* __restrict__ wcat, u16* __restrict__ wgb, u16* __restrict__ wmb) {
    int i = blockIdx.x * 256 + threadIdx.x;   // grid covers 131072
    if (i < 131072) {
        wcat[i]          = f2bf(wphi[i]);
        wcat[131072 + i] = f2bf(wtheta[i]);
        wgb[i]           = f2bf(wg[i]);
        wmb[i]           = f2bf(wm[i]);
    }
}

// ---------- x (512,4096) fp32 -> xt (4096,512) bf16, batch via blockIdx.z ----------
__global__ __launch_bounds__(256) void transpose_convert(
        const float* __restrict__ x, u16* __restrict__ xt) {
    __shared__ float t[64][65];
    const float* xb = x + (long long)blockIdx.z * 512 * 4096;
    u16* xtb = xt + (long long)blockIdx.z * 4096 * 512;
    const int p0 = blockIdx.x * 64, c0 = blockIdx.y * 64;
    const int tp = threadIdx.x & 63, tr = threadIdx.x >> 6;
    #pragma unroll
    for (int i = 0; i < 64; i += 4)
        t[i + tr][tp] = xb[(long long)(c0 + i + tr) * 4096 + p0 + tp];
    __syncthreads();
    #pragma unroll
    for (int i = 0; i < 64; i += 4)
        xtb[(long long)(p0 + i + tr) * 512 + c0 + tp] = f2bf(t[tp][i + tr]);
}

// ---------- TN bf16 GEMM: C[M][N] = sum_k A[m][k]*Bt[n][k]; 128x128 tile, BK=32 ----------
// EPI 0: split-store PtL/TtL (perm channel), 1: G natural bf16,
// EPI 2: attn-exp bf16 + column expsum atomics, 3: scatter Z[p][i] bf16, 4: fp32 + residual x
template <int EPI>
__global__ __launch_bounds__(256) void gemm_tn(
        const u16* __restrict__ Ag, long long sA, int lda,
        const u16* __restrict__ Bg, long long sB, int ldb,
        void* __restrict__ O0, long long sO0, void* __restrict__ O1,
        const float* __restrict__ Xres, int Ksz) {
    __shared__ __align__(16) u16 As[128 * 32];
    __shared__ __align__(16) u16 Bs[128 * 32];
    const int tid = threadIdx.x;
    const int bz = blockIdx.z;
    const u16* Ab = Ag + (long long)bz * sA;
    const u16* Bb = Bg + (long long)bz * sB;
    const int tm = blockIdx.x * 128, tn = blockIdx.y * 128;
    const int lane = tid & 63, wid = tid >> 6;
    const int wr = wid >> 1, wc = wid & 1;
    const int lm = lane & 15, kg = lane >> 4;

    f32x4 zero = {0.f, 0.f, 0.f, 0.f};
    f32x4 acc[4][4];
    #pragma unroll
    for (int i = 0; i < 4; i++)
        #pragma unroll
        for (int j = 0; j < 4; j++) acc[i][j] = zero;

    const int srow = tid >> 2;
    const int scol = (tid & 3) * 8;
    const u16* a0 = Ab + (long long)(tm + srow) * lda + scol;
    const u16* a1 = Ab + (long long)(tm + 64 + srow) * lda + scol;
    const u16* b0 = Bb + (long long)(tn + srow) * ldb + scol;
    const u16* b1 = Bb + (long long)(tn + 64 + srow) * ldb + scol;
    u16* ad0 = As + tid * 8;
    u16* ad1 = As + 2048 + tid * 8;
    u16* bd0 = Bs + tid * 8;
    u16* bd1 = Bs + 2048 + tid * 8;

    for (int k0 = 0; k0 < Ksz; k0 += 32) {
        async16(a0 + k0, ad0);
        async16(a1 + k0, ad1);
        async16(b0 + k0, bd0);
        async16(b1 + k0, bd1);
        __syncthreads();          // drains vmcnt, data visible
        bf16x8 af[4], bfr[4];
        #pragma unroll
        for (int i = 0; i < 4; i++) {
            af[i]  = ld8(As + (wr * 64 + i * 16 + lm) * 32 + kg * 8);
            bfr[i] = ld8(Bs + (wc * 64 + i * 16 + lm) * 32 + kg * 8);
        }
        #pragma unroll
        for (int i = 0; i < 4; i++)
            #pragma unroll
            for (int j = 0; j < 4; j++)
                acc[i][j] = __builtin_amdgcn_mfma_f32_16x16x32_bf16(af[i], bfr[j], acc[i][j], 0, 0, 0);
        __syncthreads();
    }

    // epilogue: C/D frag mapping col = lane&15, row = (lane>>4)*4 + r
    if constexpr (EPI == 2) {
        // attn logits fp32 in acc. P = exp(v) stored bf16 (no-max softmax; |logit|<~25),
        // column sums (over n = gm) accumulated into O1[m].
        #pragma unroll
        for (int j = 0; j < 4; j++) {
            const int gn = tn + wc * 64 + j * 16 + lm;   // m
            float csum = 0.f;
            #pragma unroll
            for (int i = 0; i < 4; i++) {
                #pragma unroll
                for (int r = 0; r < 4; r++) {
                    const int gm = tm + wr * 64 + i * 16 + kg * 4 + r;  // n
                    const float e = __expf(acc[i][j][r]);
                    ((u16*)O0)[(long long)bz * sO0 + (long long)gm * 2048 + gn] = f2bf(e);
                    csum += e;
                }
            }
            csum += __shfl_xor(csum, 16);
            csum += __shfl_xor(csum, 32);   // reduce over kg: full 64-row partial for this column
            if (lane < 16)
                atomicAdd((float*)O1 + (long long)bz * 2048 + gn, csum);
        }
    } else {
        #pragma unroll
        for (int i = 0; i < 4; i++) {
            #pragma unroll
            for (int j = 0; j < 4; j++) {
                #pragma unroll
                for (int r = 0; r < 4; r++) {
                    const int gm = tm + wr * 64 + i * 16 + kg * 4 + r;
                    const int gn = tn + wc * 64 + j * 16 + lm;
                    const float v = acc[i][j][r];
                    if constexpr (EPI == 0) {
                        // gm = p' (0..4095), gn = oc3 (0..511). phi->O0, theta->O1.
                        // C' = (p>>11)*256 + oc, same permutation for both -> K-sum invariant.
                        const int s = gm >> 11, mm = gm & 2047;
                        u16* dst = (u16*)(gn < 256 ? O0 : O1);
                        dst[(long long)bz * 1048576 + (long long)mm * 512 + s * 256 + (gn & 255)] = f2bf(v);
                    } else if constexpr (EPI == 1) {
                        // gm = oc (0..255), gn = p: G natural [oc][p]
                        ((u16*)O0)[(long long)bz * sO0 + (long long)gm * 4096 + gn] = f2bf(v);
                    } else if constexpr (EPI == 3) {
                        // gm = C (0..511), gn = n: Z[ ((C&1)<<11)|n ][ C>>1 ]
                        ((u16*)O0)[(long long)bz * sO0 +
                                   (long long)((((gm & 1) << 11) | gn)) * 256 + (gm >> 1)] = f2bf(v);
                    } else {
                        // gm = oc (0..511), gn = p: y = v + x
                        const long long off = (long long)bz * sO0 + (long long)gm * 4096 + gn;
                        ((float*)O0)[off] = v + Xres[off];
                    }
                }
            }
        }
    }
}

// ---------- fold softmax denominator into g: G[C][m] *= 1/S[m] (in place, bf16) ----------
__global__ __launch_bounds__(256) void g_scale(
        u16* __restrict__ G, const float* __restrict__ S) {
    const int b = blockIdx.y;
    const long long i = ((long long)blockIdx.x * 256 + threadIdx.x) * 8;
    const int m = (int)(i & 2047);   // 2048-wide rows in the [512][2048] flat view
    u16* p = G + (long long)b * 1048576 + i;
    u16x8 v = *(u16x8*)p;
    const float4 s0 = *(const float4*)(S + (long long)b * 2048 + m);
    const float4 s1 = *(const float4*)(S + (long long)b * 2048 + m + 4);
    float sv[8] = {s0.x, s0.y, s0.z, s0.w, s1.x, s1.y, s1.z, s1.w};
    u16x8 o;
    #pragma unroll
    for (int t = 0; t < 8; t++)
        o[t] = f2bf(bf2f(v[t]) / sv[t]);
    *(u16x8*)p = o;
}

// ---------- launch ----------
extern "C" void kernel_launch(void* const* d_in, const int* in_sizes, int n_in,
                              void* d_out, int out_size, void* d_ws, size_t ws_size,
                              hipStream_t stream) {
    const float* x      = (const float*)d_in[0];
    const float* w_phi  = (const float*)d_in[1];
    const float* w_theta= (const float*)d_in[2];
    const float* w_g    = (const float*)d_in[3];
    const float* w_mask = (const float*)d_in[4];
    float* y = (float*)d_out;

    const size_t MB = 1ull << 20;
    char* ws = (char*)d_ws;

    if (ws_size >= 148 * MB) {
        // ---- full-batch path (peak 148 MiB) ----
        // lifetimes: xt dead after K1b (Z aliases it); PtL/TtL dead after K2.
        u16*   xt     = (u16*)(ws);              // 32 MiB [b][4096][512]
        u16*   Z      = (u16*)(ws);              // 16 MiB (aliases xt) [b][4096][256]
        u16*   PtL    = (u16*)(ws + 32 * MB);    // 16 MiB [b][2048][512]
        u16*   TtL    = (u16*)(ws + 48 * MB);    // 16 MiB
        u16*   G      = (u16*)(ws + 64 * MB);    // 16 MiB [b][256][4096]
        u16*   wcat   = (u16*)(ws + 80 * MB);    // 0.5 MiB
        u16*   wgb    = (u16*)(ws + 81 * MB);    // 0.25 MiB
        u16*   wmb    = (u16*)(ws + 82 * MB);    // 0.25 MiB
        float* colsum = (float*)(ws + 83 * MB);  // 64 KiB [b][2048]
        u16*   attnb  = (u16*)(ws + 84 * MB);    // 64 MiB [b][2048(n)][2048(m)]

        convert_w<<<512, 256, 0, stream>>>(w_phi, w_theta, w_g, w_mask, wcat, wgb, wmb);
        transpose_convert<<<dim3(64, 8, 8), 256, 0, stream>>>(x, xt);
        hipMemsetAsync(colsum, 0, 8 * 2048 * sizeof(float), stream);

        gemm_tn<0><<<dim3(32, 4, 8), 256, 0, stream>>>(
            xt, 2097152, 512, wcat, 0, 512, PtL, 1048576, TtL, nullptr, 512);
        gemm_tn<1><<<dim3(2, 32, 8), 256, 0, stream>>>(
            wgb, 0, 512, xt, 2097152, 512, G, 1048576, nullptr, nullptr, 512);
        gemm_tn<2><<<dim3(16, 16, 8), 256, 0, stream>>>(
            TtL, 1048576, 512, PtL, 1048576, 512, attnb, 4194304, colsum, nullptr, 512);
        g_scale<<<dim3(512, 8), 256, 0, stream>>>(G, colsum);
        gemm_tn<3><<<dim3(4, 16, 8), 256, 0, stream>>>(
            G, 1048576, 2048, attnb, 4194304, 2048, Z, 1048576, nullptr, nullptr, 2048);
        gemm_tn<4><<<dim3(4, 32, 8), 256, 0, stream>>>(
            wmb, 0, 256, Z, 1048576, 256, y, 2097152, nullptr, x, 256);
    } else if (ws_size >= 20 * MB) {
        // ---- per-batch fallback (peak 19.01 MiB) ----
        u16*   xt     = (u16*)(ws);                        // 4 MiB [4096][512]
        u16*   Z      = (u16*)(ws);                        // 2 MiB (aliases xt)
        u16*   PtL    = (u16*)(ws + 4 * MB);               // 2 MiB
        u16*   TtL    = (u16*)(ws + 6 * MB);               // 2 MiB
        u16*   G      = (u16*)(ws + 8 * MB);               // 2 MiB
        u16*   attnb  = (u16*)(ws + 10 * MB);              // 8 MiB
        u16*   wcat   = (u16*)(ws + 18 * MB);              // 0.5 MiB
        u16*   wgb    = (u16*)(ws + 18 * MB + 512 * 1024); // 0.25 MiB
        u16*   wmb    = (u16*)(ws + 18 * MB + 768 * 1024); // 0.25 MiB
        float* colsum = (float*)(ws + 19 * MB);            // 8 KiB

        convert_w<<<512, 256, 0, stream>>>(w_phi, w_theta, w_g, w_mask, wcat, wgb, wmb);
        for (int b = 0; b < 8; b++) {
            const float* xb = x + (long long)b * 2097152;
            float* yb = y + (long long)b * 2097152;
            transpose_convert<<<dim3(64, 8, 1), 256, 0, stream>>>(xb, xt);
            hipMemsetAsync(colsum, 0, 2048 * sizeof(float), stream);
            gemm_tn<0><<<dim3(32, 4, 1), 256, 0, stream>>>(
                xt, 0, 512, wcat, 0, 512, PtL, 0, TtL, nullptr, 512);
            gemm_tn<1><<<dim3(2, 32, 1), 256, 0, stream>>>(
                wgb, 0, 512, xt, 0, 512, G, 0, nullptr, nullptr, 512);
            gemm_tn<2><<<dim3(16, 16, 1), 256, 0, stream>>>(
                TtL, 0, 512, PtL, 0, 512, attnb, 0, colsum, nullptr, 512);
            g_scale<<<dim3(512, 1), 256, 0, stream>>>(G, colsum);
            gemm_tn<3><<<dim3(4, 16, 1), 256, 0, stream>>>(
                G, 0, 2048, attnb, 0, 2048, Z, 0, nullptr, nullptr, 2048);
            gemm_tn<4><<<dim3(4, 32, 1), 256, 0, stream>>>(
                wmb, 0, 256, Z, 0, 256, yb, 0, nullptr, xb, 256);
        }
    }
    // else: workspace too small for any schedule; bail cleanly (no OOB writes).
    (void)in_sizes; (void)n_in; (void)out_size;
}

// Round 8
// 305.925 us; speedup vs baseline: 1.1011x; 1.1011x over previous
//
#include <hip/hip_runtime.h>

typedef unsigned short u16;
typedef __bf16 bf16x8 __attribute__((ext_vector_type(8)));
typedef unsigned short u16x8 __attribute__((ext_vector_type(8)));
typedef float f32x4 __attribute__((ext_vector_type(4)));

// ---------- helpers ----------
__device__ __forceinline__ u16 f2bf(float f) {
    unsigned u = __float_as_uint(f);
    unsigned r = u + 0x7fffu + ((u >> 16) & 1u);   // round-to-nearest-even
    return (u16)(r >> 16);
}
__device__ __forceinline__ float bf2f(u16 v) {
    return __uint_as_float(((unsigned)v) << 16);
}

__device__ __forceinline__ void async16(const void* g, void* l) {
    // global -> LDS direct copy, 16B per lane. LDS dest linear per wave.
    __builtin_amdgcn_global_load_lds(
        (__attribute__((address_space(1))) void*)(unsigned long long)g,
        (__attribute__((address_space(3))) void*)l, 16, 0, 0);
}

__device__ __forceinline__ bf16x8 ld8(const u16* p) {
    return __builtin_bit_cast(bf16x8, *(const u16x8*)p);
}

// ---------- weight convert: wcat=[w_phi;w_theta] (512x512), wg (256x512), wm (512x256) ----------
__global__ __launch_bounds__(256) void convert_w(
        const float* __restrict__ wphi, const float* __restrict__ wtheta,
        const float* __restrict__ wg, const float* __restrict__ wm,
        u16* __restrict__ wcat, u16* __restrict__ wgb, u16* __restrict__ wmb) {
    int i = blockIdx.x * 256 + threadIdx.x;   // grid covers 131072
    if (i < 131072) {
        wcat[i]          = f2bf(wphi[i]);
        wcat[131072 + i] = f2bf(wtheta[i]);
        wgb[i]           = f2bf(wg[i]);
        wmb[i]           = f2bf(wm[i]);
    }
}

// ---------- x (512,4096) fp32 -> xt (4096,512) bf16, batch via blockIdx.z ----------
__global__ __launch_bounds__(256) void transpose_convert(
        const float* __restrict__ x, u16* __restrict__ xt) {
    __shared__ float t[64][65];
    const float* xb = x + (long long)blockIdx.z * 512 * 4096;
    u16* xtb = xt + (long long)blockIdx.z * 4096 * 512;
    const int p0 = blockIdx.x * 64, c0 = blockIdx.y * 64;
    const int tp = threadIdx.x & 63, tr = threadIdx.x >> 6;
    #pragma unroll
    for (int i = 0; i < 64; i += 4)
        t[i + tr][tp] = xb[(long long)(c0 + i + tr) * 4096 + p0 + tp];
    __syncthreads();
    #pragma unroll
    for (int i = 0; i < 64; i += 4)
        xtb[(long long)(p0 + i + tr) * 512 + c0 + tp] = f2bf(t[tp][i + tr]);
}

// ---------- TN bf16 GEMM: C[M][N] = sum_k A[m][k]*Bt[n][k]; 128x128 tile, BK=64 ----------
// LDS layout: [row][8 slots of 16B], slot XOR-swizzled by (row&7); global source
// pre-swizzled so global_load_lds dest stays linear (both-sides-or-neither rule).
// DBUF=1: double-buffered 2-phase pipeline (64 KiB LDS, for grid-limited kernels).
// EPI 0: split-store PtL/TtL (perm channel), 1: G natural bf16,
// EPI 2: attn-exp bf16 + column expsum atomics, 3: scatter Z[p][i] bf16, 4: fp32 + residual x
template <int EPI, bool DBUF>
__global__ __launch_bounds__(256) void gemm_tn(
        const u16* __restrict__ Ag, long long sA, int lda,
        const u16* __restrict__ Bg, long long sB, int ldb,
        void* __restrict__ O0, long long sO0, void* __restrict__ O1,
        const float* __restrict__ Xres, int Ksz) {
    __shared__ __align__(16) u16 As[DBUF ? 2 : 1][8192];
    __shared__ __align__(16) u16 Bs[DBUF ? 2 : 1][8192];
    const int tid = threadIdx.x;
    const int bz = blockIdx.z;
    const u16* Ab = Ag + (long long)bz * sA;
    const u16* Bb = Bg + (long long)bz * sB;
    const int tm = blockIdx.x * 128, tn = blockIdx.y * 128;
    const int lane = tid & 63, wid = tid >> 6;
    const int wr = wid >> 1, wc = wid & 1;
    const int lm = lane & 15, kg = lane >> 4;

    f32x4 zero = {0.f, 0.f, 0.f, 0.f};
    f32x4 acc[4][4];
    #pragma unroll
    for (int i = 0; i < 4; i++)
        #pragma unroll
        for (int j = 0; j < 4; j++) acc[i][j] = zero;

    // staging: thread -> (row = tid>>3 (+32k), slot = tid&7); source k pre-swizzled
    const int srow = tid >> 3, sslot = tid & 7;
    const int swk = (sslot ^ (srow & 7)) << 3;
    const long long aoff = (long long)(tm + srow) * lda + swk;
    const long long boff = (long long)(tn + srow) * ldb + swk;

    // fragment read: row = woff+i*16+lm, slot' = (ks*4+kg) ^ (lm&7)
    const int s0 = (kg ^ (lm & 7)) << 3;           // elem offset, ks=0
    const int arow = (wr * 64 + lm) << 6;
    const int brow = (wc * 64 + lm) << 6;

#define STAGE(bi, k0) do {                                                  \
    const u16* a_ = Ab + aoff + (k0); const u16* b_ = Bb + boff + (k0);     \
    u16* ad = &As[bi][tid * 8];       u16* bd = &Bs[bi][tid * 8];           \
    async16(a_,            ad);                                             \
    async16(a_ + 32 * lda, ad + 2048);                                      \
    async16(a_ + 64 * lda, ad + 4096);                                      \
    async16(a_ + 96 * lda, ad + 6144);                                      \
    async16(b_,            bd);                                             \
    async16(b_ + 32 * ldb, bd + 2048);                                      \
    async16(b_ + 64 * ldb, bd + 4096);                                      \
    async16(b_ + 96 * ldb, bd + 6144);                                      \
} while (0)

#define TILE_COMPUTE(bi) do {                                               \
    _Pragma("unroll")                                                       \
    for (int ks = 0; ks < 2; ++ks) {                                        \
        const int so = s0 ^ (ks << 5);                                      \
        bf16x8 a_[4], b_[4];                                                \
        _Pragma("unroll")                                                   \
        for (int i = 0; i < 4; i++) {                                       \
            a_[i] = ld8(&As[bi][arow + (i << 10) + so]);                    \
            b_[i] = ld8(&Bs[bi][brow + (i << 10) + so]);                    \
        }                                                                   \
        _Pragma("unroll")                                                   \
        for (int i = 0; i < 4; i++)                                         \
            _Pragma("unroll")                                               \
            for (int j = 0; j < 4; j++)                                     \
                acc[i][j] = __builtin_amdgcn_mfma_f32_16x16x32_bf16(        \
                    a_[i], b_[j], acc[i][j], 0, 0, 0);                      \
    }                                                                       \
} while (0)

    const int nt = Ksz >> 6;
    if constexpr (DBUF) {
        // 2-phase: STAGE(next) issued before compute(cur); one vmcnt(0)+barrier
        // per K-step (loads fly across the MFMA block).
        STAGE(0, 0);
        __syncthreads();
        for (int t = 0; t < nt; ++t) {
            const int cur = t & 1;
            if (t + 1 < nt) STAGE(cur ^ 1, (t + 1) << 6);
            TILE_COMPUTE(cur);
            asm volatile("s_waitcnt vmcnt(0)" ::: "memory");
            __builtin_amdgcn_sched_barrier(0);
            __builtin_amdgcn_s_barrier();
            __builtin_amdgcn_sched_barrier(0);
        }
    } else {
        for (int t = 0; t < nt; ++t) {
            STAGE(0, t << 6);
            __syncthreads();
            TILE_COMPUTE(0);
            __syncthreads();
        }
    }
#undef STAGE
#undef TILE_COMPUTE

    // epilogue: C/D frag mapping col = lane&15, row = (lane>>4)*4 + r
    if constexpr (EPI == 2) {
        // attn logits fp32 in acc. P = exp(v) stored bf16 (no-max softmax; |logit|<~25),
        // column sums (over n = gm) accumulated into O1[m].
        #pragma unroll
        for (int j = 0; j < 4; j++) {
            const int gn = tn + wc * 64 + j * 16 + lm;   // m
            float csum = 0.f;
            #pragma unroll
            for (int i = 0; i < 4; i++) {
                #pragma unroll
                for (int r = 0; r < 4; r++) {
                    const int gm = tm + wr * 64 + i * 16 + kg * 4 + r;  // n
                    const float e = __expf(acc[i][j][r]);
                    ((u16*)O0)[(long long)bz * sO0 + (long long)gm * 2048 + gn] = f2bf(e);
                    csum += e;
                }
            }
            csum += __shfl_xor(csum, 16);
            csum += __shfl_xor(csum, 32);   // reduce over kg: full 64-row partial for this column
            if (lane < 16)
                atomicAdd((float*)O1 + (long long)bz * 2048 + gn, csum);
        }
    } else {
        #pragma unroll
        for (int i = 0; i < 4; i++) {
            #pragma unroll
            for (int j = 0; j < 4; j++) {
                #pragma unroll
                for (int r = 0; r < 4; r++) {
                    const int gm = tm + wr * 64 + i * 16 + kg * 4 + r;
                    const int gn = tn + wc * 64 + j * 16 + lm;
                    const float v = acc[i][j][r];
                    if constexpr (EPI == 0) {
                        // gm = p' (0..4095), gn = oc3 (0..511). phi->O0, theta->O1.
                        // C' = (p>>11)*256 + oc, same permutation for both -> K-sum invariant.
                        const int s = gm >> 11, mm = gm & 2047;
                        u16* dst = (u16*)(gn < 256 ? O0 : O1);
                        dst[(long long)bz * 1048576 + (long long)mm * 512 + s * 256 + (gn & 255)] = f2bf(v);
                    } else if constexpr (EPI == 1) {
                        // gm = oc (0..255), gn = p: G natural [oc][p]
                        ((u16*)O0)[(long long)bz * sO0 + (long long)gm * 4096 + gn] = f2bf(v);
                    } else if constexpr (EPI == 3) {
                        // gm = C (0..511), gn = n: Z[ ((C&1)<<11)|n ][ C>>1 ]
                        ((u16*)O0)[(long long)bz * sO0 +
                                   (long long)((((gm & 1) << 11) | gn)) * 256 + (gm >> 1)] = f2bf(v);
                    } else {
                        // gm = oc (0..511), gn = p: y = v + x
                        const long long off = (long long)bz * sO0 + (long long)gm * 4096 + gn;
                        ((float*)O0)[off] = v + Xres[off];
                    }
                }
            }
        }
    }
}

// ---------- fold softmax denominator into g: G[C][m] *= 1/S[m] (in place, bf16) ----------
__global__ __launch_bounds__(256) void g_scale(
        u16* __restrict__ G, const float* __restrict__ S) {
    const int b = blockIdx.y;
    const long long i = ((long long)blockIdx.x * 256 + threadIdx.x) * 8;
    const int m = (int)(i & 2047);   // 2048-wide rows in the [512][2048] flat view
    u16* p = G + (long long)b * 1048576 + i;
    u16x8 v = *(u16x8*)p;
    const float4 s0 = *(const float4*)(S + (long long)b * 2048 + m);
    const float4 s1 = *(const float4*)(S + (long long)b * 2048 + m + 4);
    float sv[8] = {s0.x, s0.y, s0.z, s0.w, s1.x, s1.y, s1.z, s1.w};
    u16x8 o;
    #pragma unroll
    for (int t = 0; t < 8; t++)
        o[t] = f2bf(bf2f(v[t]) / sv[t]);
    *(u16x8*)p = o;
}

// ---------- launch ----------
extern "C" void kernel_launch(void* const* d_in, const int* in_sizes, int n_in,
                              void* d_out, int out_size, void* d_ws, size_t ws_size,
                              hipStream_t stream) {
    const float* x      = (const float*)d_in[0];
    const float* w_phi  = (const float*)d_in[1];
    const float* w_theta= (const float*)d_in[2];
    const float* w_g    = (const float*)d_in[3];
    const float* w_mask = (const float*)d_in[4];
    float* y = (float*)d_out;

    const size_t MB = 1ull << 20;
    char* ws = (char*)d_ws;

    if (ws_size >= 148 * MB) {
        // ---- full-batch path (peak 148 MiB) ----
        // lifetimes: xt dead after K1b (Z aliases it); PtL/TtL dead after K2.
        u16*   xt     = (u16*)(ws);              // 32 MiB [b][4096][512]
        u16*   Z      = (u16*)(ws);              // 16 MiB (aliases xt) [b][4096][256]
        u16*   PtL    = (u16*)(ws + 32 * MB);    // 16 MiB [b][2048][512]
        u16*   TtL    = (u16*)(ws + 48 * MB);    // 16 MiB
        u16*   G      = (u16*)(ws + 64 * MB);    // 16 MiB [b][256][4096]
        u16*   wcat   = (u16*)(ws + 80 * MB);    // 0.5 MiB
        u16*   wgb    = (u16*)(ws + 81 * MB);    // 0.25 MiB
        u16*   wmb    = (u16*)(ws + 82 * MB);    // 0.25 MiB
        float* colsum = (float*)(ws + 83 * MB);  // 64 KiB [b][2048]
        u16*   attnb  = (u16*)(ws + 84 * MB);    // 64 MiB [b][2048(n)][2048(m)]

        convert_w<<<512, 256, 0, stream>>>(w_phi, w_theta, w_g, w_mask, wcat, wgb, wmb);
        transpose_convert<<<dim3(64, 8, 8), 256, 0, stream>>>(x, xt);
        hipMemsetAsync(colsum, 0, 8 * 2048 * sizeof(float), stream);

        gemm_tn<0, false><<<dim3(32, 4, 8), 256, 0, stream>>>(
            xt, 2097152, 512, wcat, 0, 512, PtL, 1048576, TtL, nullptr, 512);
        gemm_tn<1, false><<<dim3(2, 32, 8), 256, 0, stream>>>(
            wgb, 0, 512, xt, 2097152, 512, G, 1048576, nullptr, nullptr, 512);
        gemm_tn<2, false><<<dim3(16, 16, 8), 256, 0, stream>>>(
            TtL, 1048576, 512, PtL, 1048576, 512, attnb, 4194304, colsum, nullptr, 512);
        g_scale<<<dim3(512, 8), 256, 0, stream>>>(G, colsum);
        gemm_tn<3, true><<<dim3(4, 16, 8), 256, 0, stream>>>(
            G, 1048576, 2048, attnb, 4194304, 2048, Z, 1048576, nullptr, nullptr, 2048);
        gemm_tn<4, false><<<dim3(4, 32, 8), 256, 0, stream>>>(
            wmb, 0, 256, Z, 1048576, 256, y, 2097152, nullptr, x, 256);
    } else if (ws_size >= 20 * MB) {
        // ---- per-batch fallback (peak 19.01 MiB) ----
        u16*   xt     = (u16*)(ws);                        // 4 MiB [4096][512]
        u16*   Z      = (u16*)(ws);                        // 2 MiB (aliases xt)
        u16*   PtL    = (u16*)(ws + 4 * MB);               // 2 MiB
        u16*   TtL    = (u16*)(ws + 6 * MB);               // 2 MiB
        u16*   G      = (u16*)(ws + 8 * MB);               // 2 MiB
        u16*   attnb  = (u16*)(ws + 10 * MB);              // 8 MiB
        u16*   wcat   = (u16*)(ws + 18 * MB);              // 0.5 MiB
        u16*   wgb    = (u16*)(ws + 18 * MB + 512 * 1024); // 0.25 MiB
        u16*   wmb    = (u16*)(ws + 18 * MB + 768 * 1024); // 0.25 MiB
        float* colsum = (float*)(ws + 19 * MB);            // 8 KiB

        convert_w<<<512, 256, 0, stream>>>(w_phi, w_theta, w_g, w_mask, wcat, wgb, wmb);
        for (int b = 0; b < 8; b++) {
            const float* xb = x + (long long)b * 2097152;
            float* yb = y + (long long)b * 2097152;
            transpose_convert<<<dim3(64, 8, 1), 256, 0, stream>>>(xb, xt);
            hipMemsetAsync(colsum, 0, 2048 * sizeof(float), stream);
            gemm_tn<0, false><<<dim3(32, 4, 1), 256, 0, stream>>>(
                xt, 0, 512, wcat, 0, 512, PtL, 0, TtL, nullptr, 512);
            gemm_tn<1, false><<<dim3(2, 32, 1), 256, 0, stream>>>(
                wgb, 0, 512, xt, 0, 512, G, 0, nullptr, nullptr, 512);
            gemm_tn<2, false><<<dim3(16, 16, 1), 256, 0, stream>>>(
                TtL, 0, 512, PtL, 0, 512, attnb, 0, colsum, nullptr, 512);
            g_scale<<<dim3(512, 1), 256, 0, stream>>>(G, colsum);
            gemm_tn<3, true><<<dim3(4, 16, 1), 256, 0, stream>>>(
                G, 0, 2048, attnb, 0, 2048, Z, 0, nullptr, nullptr, 2048);
            gemm_tn<4, false><<<dim3(4, 32, 1), 256, 0, stream>>>(
                wmb, 0, 256, Z, 0, 256, yb, 0, nullptr, xb, 256);
        }
    }
    // else: workspace too small for any schedule; bail cleanly (no OOB writes).
    (void)in_sizes; (void)n_in; (void)out_size;
}

// Round 11
// 302.093 us; speedup vs baseline: 1.1150x; 1.0127x over previous
//
#include <hip/hip_runtime.h>

typedef unsigned short u16;
typedef __bf16 bf16x8 __attribute__((ext_vector_type(8)));
typedef unsigned short u16x8 __attribute__((ext_vector_type(8)));
typedef float f32x4 __attribute__((ext_vector_type(4)));

// ---------- helpers ----------
__device__ __forceinline__ u16 f2bf(float f) {
    unsigned u = __float_as_uint(f);
    unsigned r = u + 0x7fffu + ((u >> 16) & 1u);   // round-to-nearest-even
    return (u16)(r >> 16);
}
__device__ __forceinline__ float bf2f(u16 v) {
    return __uint_as_float(((unsigned)v) << 16);
}

__device__ __forceinline__ void async16(const void* g, void* l) {
    // global -> LDS direct copy, 16B per lane. LDS dest linear per wave.
    __builtin_amdgcn_global_load_lds(
        (__attribute__((address_space(1))) void*)(unsigned long long)g,
        (__attribute__((address_space(3))) void*)l, 16, 0, 0);
}

__device__ __forceinline__ bf16x8 ld8(const u16* p) {
    return __builtin_bit_cast(bf16x8, *(const u16x8*)p);
}

// ---------- weight convert: wcat=[w_phi;w_theta] (512x512), wg (256x512), wm (512x256) ----------
__global__ __launch_bounds__(256) void convert_w(
        const float* __restrict__ wphi, const float* __restrict__ wtheta,
        const float* __restrict__ wg, const float* __restrict__ wm,
        u16* __restrict__ wcat, u16* __restrict__ wgb, u16* __restrict__ wmb) {
    int i = blockIdx.x * 256 + threadIdx.x;   // grid covers 131072
    if (i < 131072) {
        wcat[i]          = f2bf(wphi[i]);
        wcat[131072 + i] = f2bf(wtheta[i]);
        wgb[i]           = f2bf(wg[i]);
        wmb[i]           = f2bf(wm[i]);
    }
}

// ---------- x (512,4096) fp32 -> xt (4096,512) bf16, batch via blockIdx.z ----------
__global__ __launch_bounds__(256) void transpose_convert(
        const float* __restrict__ x, u16* __restrict__ xt) {
    __shared__ float t[64][65];
    const float* xb = x + (long long)blockIdx.z * 512 * 4096;
    u16* xtb = xt + (long long)blockIdx.z * 4096 * 512;
    const int p0 = blockIdx.x * 64, c0 = blockIdx.y * 64;
    const int tp = threadIdx.x & 63, tr = threadIdx.x >> 6;
    #pragma unroll
    for (int i = 0; i < 64; i += 4)
        t[i + tr][tp] = xb[(long long)(c0 + i + tr) * 4096 + p0 + tp];
    __syncthreads();
    #pragma unroll
    for (int i = 0; i < 64; i += 4)
        xtb[(long long)(p0 + i + tr) * 512 + c0 + tp] = f2bf(t[tp][i + tr]);
}

// ---------- TN bf16 GEMM: C[M][N] = sum_k A[m][k]*Bt[n][k]; 128x128 tile, BK=64 ----------
// LDS layout: [row][8 slots of 16B], slot XOR-swizzled by (row&7); global source
// pre-swizzled so global_load_lds dest stays linear (both-sides-or-neither rule).
// XCD-chunked bijective blockIdx swizzle (m204): hw id h -> orig=(h&7)*(nwg/8)+(h>>3)
// so each XCD owns contiguous batches (operand panels become L2-resident).
// DBUF=1: double-buffered pipeline with COUNTED vmcnt(8) waited BEFORE compute
// (prev-tile loads had a full iteration to fly); vmcnt(0) only on last tile.
// EPI 0: split-store PtL/TtL (perm channel), 1: G natural bf16,
// EPI 2: attn-exp bf16 + column expsum atomics, 3: scatter Z[p][i] bf16, 4: fp32 + residual x
template <int EPI, bool DBUF>
__global__ __launch_bounds__(256) void gemm_tn(
        const u16* __restrict__ Ag, long long sA, int lda,
        const u16* __restrict__ Bg, long long sB, int ldb,
        void* __restrict__ O0, long long sO0, void* __restrict__ O1,
        const float* __restrict__ Xres, int Ksz) {
    __shared__ __align__(16) u16 As[DBUF ? 2 : 1][8192];
    __shared__ __align__(16) u16 Bs[DBUF ? 2 : 1][8192];
    const int tid = threadIdx.x;

    // XCD-chunked bijective remap (all grids have nwg % 8 == 0)
    const int nwg = gridDim.x * gridDim.y * gridDim.z;
    const int h = blockIdx.x + gridDim.x * (blockIdx.y + gridDim.y * blockIdx.z);
    const int orig = (h & 7) * (nwg >> 3) + (h >> 3);
    const int bx = orig % gridDim.x;
    const int rem = orig / gridDim.x;
    const int by = rem % gridDim.y;
    const int bz = rem / gridDim.y;

    const u16* Ab = Ag + (long long)bz * sA;
    const u16* Bb = Bg + (long long)bz * sB;
    const int tm = bx * 128, tn = by * 128;
    const int lane = tid & 63, wid = tid >> 6;
    const int wr = wid >> 1, wc = wid & 1;
    const int lm = lane & 15, kg = lane >> 4;

    f32x4 zero = {0.f, 0.f, 0.f, 0.f};
    f32x4 acc[4][4];
    #pragma unroll
    for (int i = 0; i < 4; i++)
        #pragma unroll
        for (int j = 0; j < 4; j++) acc[i][j] = zero;

    // staging: thread -> (row = tid>>3 (+32k), slot = tid&7); source k pre-swizzled
    const int srow = tid >> 3, sslot = tid & 7;
    const int swk = (sslot ^ (srow & 7)) << 3;
    const long long aoff = (long long)(tm + srow) * lda + swk;
    const long long boff = (long long)(tn + srow) * ldb + swk;

    // fragment read: row = woff+i*16+lm, slot' = (ks*4+kg) ^ (lm&7)
    const int s0 = (kg ^ (lm & 7)) << 3;           // elem offset, ks=0
    const int arow = (wr * 64 + lm) << 6;
    const int brow = (wc * 64 + lm) << 6;

#define STAGE(bi, k0) do {                                                  \
    const u16* a_ = Ab + aoff + (k0); const u16* b_ = Bb + boff + (k0);     \
    u16* ad = &As[bi][tid * 8];       u16* bd = &Bs[bi][tid * 8];           \
    async16(a_,            ad);                                             \
    async16(a_ + 32 * lda, ad + 2048);                                      \
    async16(a_ + 64 * lda, ad + 4096);                                      \
    async16(a_ + 96 * lda, ad + 6144);                                      \
    async16(b_,            bd);                                             \
    async16(b_ + 32 * ldb, bd + 2048);                                      \
    async16(b_ + 64 * ldb, bd + 4096);                                      \
    async16(b_ + 96 * ldb, bd + 6144);                                      \
} while (0)

#define TILE_COMPUTE(bi) do {                                               \
    _Pragma("unroll")                                                       \
    for (int ks = 0; ks < 2; ++ks) {                                        \
        const int so = s0 ^ (ks << 5);                                      \
        bf16x8 a_[4], b_[4];                                                \
        _Pragma("unroll")                                                   \
        for (int i = 0; i < 4; i++) {                                       \
            a_[i] = ld8(&As[bi][arow + (i << 10) + so]);                    \
            b_[i] = ld8(&Bs[bi][brow + (i << 10) + so]);                    \
        }                                                                   \
        _Pragma("unroll")                                                   \
        for (int i = 0; i < 4; i++)                                         \
            _Pragma("unroll")                                               \
            for (int j = 0; j < 4; j++)                                     \
                acc[i][j] = __builtin_amdgcn_mfma_f32_16x16x32_bf16(        \
                    a_[i], b_[j], acc[i][j], 0, 0, 0);                      \
    }                                                                       \
} while (0)

    const int nt = Ksz >> 6;
    if constexpr (DBUF) {
        STAGE(0, 0);
        for (int t = 0; t < nt; ++t) {
            const int cur = t & 1;
            if (t + 1 < nt) {
                STAGE(cur ^ 1, (t + 1) << 6);
                // 8 next-tile loads in flight; wait only for cur's 8 (issued
                // a full iteration ago).
                asm volatile("s_waitcnt vmcnt(8)" ::: "memory");
            } else {
                asm volatile("s_waitcnt vmcnt(0)" ::: "memory");
            }
            __builtin_amdgcn_sched_barrier(0);
            __builtin_amdgcn_s_barrier();      // cur staged data visible to all
            __builtin_amdgcn_sched_barrier(0);
            TILE_COMPUTE(cur);
            __builtin_amdgcn_s_barrier();      // all reads of cur done before
            __builtin_amdgcn_sched_barrier(0); // next iter's STAGE overwrites it
        }
    } else {
        for (int t = 0; t < nt; ++t) {
            STAGE(0, t << 6);
            __syncthreads();
            TILE_COMPUTE(0);
            __syncthreads();
        }
    }
#undef STAGE
#undef TILE_COMPUTE

    // epilogue: C/D frag mapping col = lane&15, row = (lane>>4)*4 + r
    if constexpr (EPI == 2) {
        // attn logits fp32 in acc. P = exp(v) stored bf16 (no-max softmax; |logit|<~25),
        // column sums (over n = gm) accumulated into O1[m].
        #pragma unroll
        for (int j = 0; j < 4; j++) {
            const int gn = tn + wc * 64 + j * 16 + lm;   // m
            float csum = 0.f;
            #pragma unroll
            for (int i = 0; i < 4; i++) {
                #pragma unroll
                for (int r = 0; r < 4; r++) {
                    const int gm = tm + wr * 64 + i * 16 + kg * 4 + r;  // n
                    const float e = __expf(acc[i][j][r]);
                    ((u16*)O0)[(long long)bz * sO0 + (long long)gm * 2048 + gn] = f2bf(e);
                    csum += e;
                }
            }
            csum += __shfl_xor(csum, 16);
            csum += __shfl_xor(csum, 32);   // reduce over kg: full 64-row partial for this column
            if (lane < 16)
                atomicAdd((float*)O1 + (long long)bz * 2048 + gn, csum);
        }
    } else {
        #pragma unroll
        for (int i = 0; i < 4; i++) {
            #pragma unroll
            for (int j = 0; j < 4; j++) {
                #pragma unroll
                for (int r = 0; r < 4; r++) {
                    const int gm = tm + wr * 64 + i * 16 + kg * 4 + r;
                    const int gn = tn + wc * 64 + j * 16 + lm;
                    const float v = acc[i][j][r];
                    if constexpr (EPI == 0) {
                        // gm = p' (0..4095), gn = oc3 (0..511). phi->O0, theta->O1.
                        // C' = (p>>11)*256 + oc, same permutation for both -> K-sum invariant.
                        const int s = gm >> 11, mm = gm & 2047;
                        u16* dst = (u16*)(gn < 256 ? O0 : O1);
                        dst[(long long)bz * 1048576 + (long long)mm * 512 + s * 256 + (gn & 255)] = f2bf(v);
                    } else if constexpr (EPI == 1) {
                        // gm = oc (0..255), gn = p: G natural [oc][p]
                        ((u16*)O0)[(long long)bz * sO0 + (long long)gm * 4096 + gn] = f2bf(v);
                    } else if constexpr (EPI == 3) {
                        // gm = C (0..511), gn = n: Z[ ((C&1)<<11)|n ][ C>>1 ]
                        ((u16*)O0)[(long long)bz * sO0 +
                                   (long long)((((gm & 1) << 11) | gn)) * 256 + (gm >> 1)] = f2bf(v);
                    } else {
                        // gm = oc (0..511), gn = p: y = v + x
                        const long long off = (long long)bz * sO0 + (long long)gm * 4096 + gn;
                        ((float*)O0)[off] = v + Xres[off];
                    }
                }
            }
        }
    }
}

// ---------- fold softmax denominator into g: G[C][m] *= 1/S[m] (in place, bf16) ----------
__global__ __launch_bounds__(256) void g_scale(
        u16* __restrict__ G, const float* __restrict__ S) {
    const int b = blockIdx.y;
    const long long i = ((long long)blockIdx.x * 256 + threadIdx.x) * 8;
    const int m = (int)(i & 2047);   // 2048-wide rows in the [512][2048] flat view
    u16* p = G + (long long)b * 1048576 + i;
    u16x8 v = *(u16x8*)p;
    const float4 s0 = *(const float4*)(S + (long long)b * 2048 + m);
    const float4 s1 = *(const float4*)(S + (long long)b * 2048 + m + 4);
    float sv[8] = {s0.x, s0.y, s0.z, s0.w, s1.x, s1.y, s1.z, s1.w};
    u16x8 o;
    #pragma unroll
    for (int t = 0; t < 8; t++)
        o[t] = f2bf(bf2f(v[t]) / sv[t]);
    *(u16x8*)p = o;
}

// ---------- launch ----------
extern "C" void kernel_launch(void* const* d_in, const int* in_sizes, int n_in,
                              void* d_out, int out_size, void* d_ws, size_t ws_size,
                              hipStream_t stream) {
    const float* x      = (const float*)d_in[0];
    const float* w_phi  = (const float*)d_in[1];
    const float* w_theta= (const float*)d_in[2];
    const float* w_g    = (const float*)d_in[3];
    const float* w_mask = (const float*)d_in[4];
    float* y = (float*)d_out;

    const size_t MB = 1ull << 20;
    char* ws = (char*)d_ws;

    if (ws_size >= 148 * MB) {
        // ---- full-batch path (peak 148 MiB) ----
        // lifetimes: xt dead after K1b (Z aliases it); PtL/TtL dead after K2.
        u16*   xt     = (u16*)(ws);              // 32 MiB [b][4096][512]
        u16*   Z      = (u16*)(ws);              // 16 MiB (aliases xt) [b][4096][256]
        u16*   PtL    = (u16*)(ws + 32 * MB);    // 16 MiB [b][2048][512]
        u16*   TtL    = (u16*)(ws + 48 * MB);    // 16 MiB
        u16*   G      = (u16*)(ws + 64 * MB);    // 16 MiB [b][256][4096]
        u16*   wcat   = (u16*)(ws + 80 * MB);    // 0.5 MiB
        u16*   wgb    = (u16*)(ws + 81 * MB);    // 0.25 MiB
        u16*   wmb    = (u16*)(ws + 82 * MB);    // 0.25 MiB
        float* colsum = (float*)(ws + 83 * MB);  // 64 KiB [b][2048]
        u16*   attnb  = (u16*)(ws + 84 * MB);    // 64 MiB [b][2048(n)][2048(m)]

        convert_w<<<512, 256, 0, stream>>>(w_phi, w_theta, w_g, w_mask, wcat, wgb, wmb);
        transpose_convert<<<dim3(64, 8, 8), 256, 0, stream>>>(x, xt);
        hipMemsetAsync(colsum, 0, 8 * 2048 * sizeof(float), stream);

        gemm_tn<0, false><<<dim3(32, 4, 8), 256, 0, stream>>>(
            xt, 2097152, 512, wcat, 0, 512, PtL, 1048576, TtL, nullptr, 512);
        gemm_tn<1, false><<<dim3(2, 32, 8), 256, 0, stream>>>(
            wgb, 0, 512, xt, 2097152, 512, G, 1048576, nullptr, nullptr, 512);
        gemm_tn<2, false><<<dim3(16, 16, 8), 256, 0, stream>>>(
            TtL, 1048576, 512, PtL, 1048576, 512, attnb, 4194304, colsum, nullptr, 512);
        g_scale<<<dim3(512, 8), 256, 0, stream>>>(G, colsum);
        gemm_tn<3, true><<<dim3(4, 16, 8), 256, 0, stream>>>(
            G, 1048576, 2048, attnb, 4194304, 2048, Z, 1048576, nullptr, nullptr, 2048);
        gemm_tn<4, false><<<dim3(4, 32, 8), 256, 0, stream>>>(
            wmb, 0, 256, Z, 1048576, 256, y, 2097152, nullptr, x, 256);
    } else if (ws_size >= 20 * MB) {
        // ---- per-batch fallback (peak 19.01 MiB) ----
        u16*   xt     = (u16*)(ws);                        // 4 MiB [4096][512]
        u16*   Z      = (u16*)(ws);                        // 2 MiB (aliases xt)
        u16*   PtL    = (u16*)(ws + 4 * MB);               // 2 MiB
        u16*   TtL    = (u16*)(ws + 6 * MB);               // 2 MiB
        u16*   G      = (u16*)(ws + 8 * MB);               // 2 MiB
        u16*   attnb  = (u16*)(ws + 10 * MB);              // 8 MiB
        u16*   wcat   = (u16*)(ws + 18 * MB);              // 0.5 MiB
        u16*   wgb    = (u16*)(ws + 18 * MB + 512 * 1024); // 0.25 MiB
        u16*   wmb    = (u16*)(ws + 18 * MB + 768 * 1024); // 0.25 MiB
        float* colsum = (float*)(ws + 19 * MB);            // 8 KiB

        convert_w<<<512, 256, 0, stream>>>(w_phi, w_theta, w_g, w_mask, wcat, wgb, wmb);
        for (int b = 0; b < 8; b++) {
            const float* xb = x + (long long)b * 2097152;
            float* yb = y + (long long)b * 2097152;
            transpose_convert<<<dim3(64, 8, 1), 256, 0, stream>>>(xb, xt);
            hipMemsetAsync(colsum, 0, 2048 * sizeof(float), stream);
            gemm_tn<0, false><<<dim3(32, 4, 1), 256, 0, stream>>>(
                xt, 0, 512, wcat, 0, 512, PtL, 0, TtL, nullptr, 512);
            gemm_tn<1, false><<<dim3(2, 32, 1), 256, 0, stream>>>(
                wgb, 0, 512, xt, 0, 512, G, 0, nullptr, nullptr, 512);
            gemm_tn<2, false><<<dim3(16, 16, 1), 256, 0, stream>>>(
                TtL, 0, 512, PtL, 0, 512, attnb, 0, colsum, nullptr, 512);
            g_scale<<<dim3(512, 1), 256, 0, stream>>>(G, colsum);
            gemm_tn<3, true><<<dim3(4, 16, 1), 256, 0, stream>>>(
                G, 0, 2048, attnb, 0, 2048, Z, 0, nullptr, nullptr, 2048);
            gemm_tn<4, false><<<dim3(4, 32, 1), 256, 0, stream>>>(
                wmb, 0, 256, Z, 0, 256, yb, 0, nullptr, xb, 256);
        }
    }
    // else: workspace too small for any schedule; bail cleanly (no OOB writes).
    (void)in_sizes; (void)n_in; (void)out_size;
}